// Round 18
// baseline (6454.664 us; speedup 1.0000x reference)
//
#include <hip/hip_runtime.h>
#include <hip/hip_bf16.h>
#include <math.h>

#define SEQL   4096
#define NITEMS 512
#define HID    256
#define NLAY   16
#define QS     64      // ring slots = 8 chunks x 8 steps
#define CHUNK  8
#define NCHUNK (SEQL / CHUNK)
#define TPB    4
#define IMGW   288     // padded row (ushort): +16-bank stagger between rows

typedef float f4 __attribute__((ext_vector_type(4)));
typedef short short8 __attribute__((ext_vector_type(8)));
typedef unsigned short u16x4 __attribute__((ext_vector_type(4)));

// Workspace layout (float offsets)
#define P_OFF   ((size_t)0)                               // P[4][SEQL][HID]
#define H_OFF   (P_OFF + (size_t)4*SEQL*HID)              // Hring[4][NLAY][QS][HID]
#define AP_OFF  (H_OFF + (size_t)4*NLAY*QS*HID)           // Apart[4][NLAY][QS][HID]
#define HF_OFF  (AP_OFF + (size_t)4*NLAY*QS*HID)          // hfinal[4][HID]
#define FLAG_OFF_FLOATS (HF_OFF + (size_t)1024)
#define NFLAGS 256

// ---------------------------------------------------------------------------
__device__ __forceinline__ float ld_coh_b32(const float* p) {
    float r;
    asm volatile("global_load_dword %0, %1, off sc0 sc1" : "=v"(r) : "v"(p));
    return r;
}
__device__ __forceinline__ void st_coh_f4(float* p, f4 v) {
    asm volatile("global_store_dwordx4 %0, %1, off sc0 sc1" :: "v"(p), "v"(v) : "memory");
}
__device__ __forceinline__ void st_coh_u32(unsigned* p, unsigned v) {
    asm volatile("global_store_dword %0, %1, off sc0 sc1" :: "v"(p), "v"(v) : "memory");
}
__device__ __forceinline__ unsigned uload(const unsigned* p) {
    return __hip_atomic_load(p, __ATOMIC_RELAXED, __HIP_MEMORY_SCOPE_AGENT);
}

#define SBAR()  { __builtin_amdgcn_s_barrier(); __builtin_amdgcn_sched_barrier(0); }
#define LGKM0() { asm volatile("s_waitcnt lgkmcnt(0)" ::: "memory"); __builtin_amdgcn_sched_barrier(0); }
#define VMW0()  { asm volatile("s_waitcnt vmcnt(0)" ::: "memory"); __builtin_amdgcn_sched_barrier(0); }
#define WAIT_PIN(reg) { asm volatile("s_waitcnt vmcnt(0)" : "+v"(reg) :: "memory"); \
                        __builtin_amdgcn_sched_barrier(0); }

__device__ __forceinline__ void spin_ge(const unsigned* p, unsigned target, bool* dead) {
    if (*dead) return;
    unsigned it = 0;
    while (uload(p) < target) {
        __builtin_amdgcn_s_sleep(1);
        if (++it > (1u << 20)) { *dead = true; break; }
    }
}

__device__ __forceinline__ float tanh_fast(float x) {
    return 1.f - __fdividef(2.f, __expf(2.f * x) + 1.f);
}

// bf16 split helpers (RNE)
__device__ __forceinline__ unsigned short bf_hi(float f) {
    unsigned u = __float_as_uint(f);
    return (unsigned short)((u + 0x7FFFu + ((u >> 16) & 1u)) >> 16);
}
__device__ __forceinline__ float bf2f(unsigned short s) {
    return __uint_as_float(((unsigned)s) << 16);
}

// o = ror8(a) + b  (16-lane rows; lane q reads lane (q-8)&15 — R10-verified)
__device__ __forceinline__ float dpp_ror8_add(float a, float b) {
    float o;
    asm volatile("v_add_f32_dpp %0, %1, %2 row_ror:8 row_mask:0xf bank_mask:0xf"
                 : "=&v"(o) : "v"(a), "v"(b));
    return o;
}

// ---------------------------------------------------------------------------
// Kernel 1: input projection P[c][t][j] = sum_k Wih0_c[j,k] * x[t,k,c]
__global__ __launch_bounds__(1024) void proj_kernel(
    const float* __restrict__ x, const float* __restrict__ Wlp,
    const float* __restrict__ Wlpv, float* __restrict__ P)
{
    __shared__ float xs[TPB][4][NITEMS];
    const int tid = threadIdx.x;
    const int t0 = blockIdx.x * TPB;

    #pragma unroll
    for (int tt = 0; tt < TPB; ++tt) {
        const float2* src = (const float2*)(x + (size_t)(t0 + tt) * NITEMS * 4);
        float2 v = src[tid];
        int e = 2 * tid;
        xs[tt][e & 3][e >> 2]       = v.x;
        xs[tt][(e + 1) & 3][e >> 2] = v.y;
    }
    __syncthreads();

    const int c = tid >> 8, j = tid & 255;
    const float* W = (c == 1) ? Wlpv : Wlp;
    const float4* row = (const float4*)(W + (size_t)j * NITEMS);
    float acc[TPB] = {0.f, 0.f, 0.f, 0.f};
    #pragma unroll 4
    for (int k4 = 0; k4 < NITEMS / 4; ++k4) {
        float4 w = row[k4];
        #pragma unroll
        for (int tt = 0; tt < TPB; ++tt) {
            float4 xv = *(const float4*)(&xs[tt][c][k4 * 4]);
            acc[tt] = fmaf(w.x, xv.x, fmaf(w.y, xv.y, fmaf(w.z, xv.z, fmaf(w.w, xv.w, acc[tt]))));
        }
    }
    #pragma unroll
    for (int tt = 0; tt < TPB; ++tt)
        P[((size_t)c * SEQL + (t0 + tt)) * HID + j] = acc[tt];
}

// ---------------------------------------------------------------------------
// Kernel 2: layer-pipelined RNN. R12 protocol, MFMA core (col-packed hi|lo),
// BANK-STAGGERED images (row stride 288 ushort = +16 banks => per-kt chunks
// tile all 32 banks), batched ds_reads, all-lane tail.
__global__ __launch_bounds__(1024, 1) void rnn_pipe(
    const float* __restrict__ lp_Wih,  const float* __restrict__ lp_Whh,
    const float* __restrict__ lp_bih,  const float* __restrict__ lp_bhh,
    const float* __restrict__ lpv_Wih, const float* __restrict__ lpv_Whh,
    const float* __restrict__ lpv_bih, const float* __restrict__ lpv_bhh,
    const float* __restrict__ P, float* __restrict__ Hring,
    float* __restrict__ Apart, float* __restrict__ hfinal,
    unsigned* __restrict__ Hflag, unsigned* __restrict__ Aflag)
{
    __shared__ __align__(16) unsigned short img[2][2][IMGW];       // B: [buf][hi/lo][k]
    __shared__ __align__(16) unsigned short stgH[CHUNK][IMGW];     // A: staged h hi
    __shared__ __align__(16) unsigned short stgL[CHUNK][IMGW];     // A: staged h lo
    __shared__ __align__(16) float apL[CHUNK][HID];                // B: inputs(+bias)
    __shared__ int pf_lds[2];

    const int b = blockIdx.x;
    if (b >= 124) return;
    const int tid = threadIdx.x;

    const int c = b / 31;
    const int r = b % 31;
    const int role = (r < NLAY) ? 0 : 1;
    const int l = (r < NLAY) ? r : (r - NLAY + 1);

    const float* Wih = (c == 1) ? lpv_Wih : lp_Wih;
    const float* Whh = (c == 1) ? lpv_Whh : lp_Whh;
    const float* bih = (c == 1) ? lpv_bih : lp_bih;
    const float* bhh = (c == 1) ? lpv_bhh : lp_bhh;

    const int RT   = tid >> 6;        // wave = row-tile 0..15
    const int lane = tid & 63;
    const int g    = lane >> 4;       // k-subgroup / D-row group
    const int col  = lane & 15;       // A row-in-tile / D col
    const int hl   = (lane >> 3) & 1; // B-col group: 0 = h_hi, 1 = h_lo
    const int m2   = tid & 255;       // staging column
    const int sA   = tid >> 8;        // staging timestep (and sA+4)
    bool dead = false;

    // ---- weights: wave RT rows 16RT+col, k = 32kt + 8g + j (layout verified R16) ----
    short8 waH[8], waL[8];
    {
        const float* Wb = (role == 0) ? (Whh + (size_t)l * HID * HID)
                                      : (Wih + (size_t)(l - 1) * HID * HID);
        const float* prow = Wb + (size_t)(16 * RT + col) * HID + 8 * g;
        #pragma unroll
        for (int kt = 0; kt < 8; ++kt) {
            f4 v0 = *(const f4*)(prow + 32 * kt);
            f4 v1 = *(const f4*)(prow + 32 * kt + 4);
            float vv[8] = {v0.x, v0.y, v0.z, v0.w, v1.x, v1.y, v1.z, v1.w};
            short8 hi8, lo8;
            #pragma unroll
            for (int jj = 0; jj < 8; ++jj) {
                unsigned short h_ = bf_hi(vv[jj]);
                hi8[jj] = (short)h_;
                lo8[jj] = (short)bf_hi(vv[jj] - bf2f(h_));
            }
            waH[kt] = hi8; waL[kt] = lo8;
        }
    }
    #pragma unroll
    for (int kt = 0; kt < 8; ++kt) asm volatile("" : "+v"(waH[kt]), "+v"(waL[kt]));

    const int m0 = 16 * RT + 4 * g;   // this lane's 4 output rows

    if (role == 0) {
        // ===================== B role =====================
        const bool l0 = (l == 0);
        const float*    Psrc  = P + (size_t)c * SEQL * HID;
        const float*    apbuf = Apart + ((size_t)(c * NLAY + l) * QS) * HID;
        const unsigned* af    = Aflag + c * NLAY + l;
        unsigned*       myHfl = Hflag + c * NLAY + l;
        const unsigned* consA = Aflag + c * NLAY + l + 1;   // valid when l<15
        float*          Hout  = Hring + ((size_t)(c * NLAY + l) * QS) * HID;
        float*          hfin  = hfinal + (size_t)c * HID;
        const float bias_m2 = bih[l * HID + m2] + bhh[l * HID + m2];

        if (tid < 256) { img[0][0][tid] = 0; img[0][1][tid] = 0; }
        LGKM0(); SBAR();

        float apn0 = 0.f, apn1 = 0.f;
        bool havePF = false;

        for (int k = 0; k < NCHUNK; ++k) {
            // ---------- chunk top ----------
            int pf2ok = 1;
            if (k >= CHUNK && l < NLAY - 1) pf2ok = pf_lds[1];
            const bool needbar = (!havePF && !l0) || !pf2ok;
            if (needbar) {
                if (tid == 0) {
                    if (!havePF && !l0) spin_ge(af, (unsigned)(k + 1), &dead);
                    if (!pf2ok) spin_ge(consA, (unsigned)(k - 7), &dead);
                }
                SBAR();
            }
            if (havePF) {
                VMW0();
                apL[sA][m2]     = apn0 + bias_m2;
                apL[sA + 4][m2] = apn1 + bias_m2;
            } else {
                float a0, a1;
                if (l0) {
                    a0 = Psrc[(size_t)(CHUNK * k + sA) * HID + m2];
                    a1 = Psrc[(size_t)(CHUNK * k + sA + 4) * HID + m2];
                } else {
                    a0 = ld_coh_b32(apbuf + (size_t)((k & 7) * CHUNK + sA) * HID + m2);
                    a1 = ld_coh_b32(apbuf + (size_t)((k & 7) * CHUNK + sA + 4) * HID + m2);
                }
                VMW0();
                apL[sA][m2]     = a0 + bias_m2;
                apL[sA + 4][m2] = a1 + bias_m2;
            }
            unsigned afv = 0u, bpv = 0u;
            const bool pollIn = (!l0) && (k + 1 < NCHUNK);
            const bool pollBp = (l < NLAY - 1) && (k + 1 >= CHUNK) && (k + 1 < NCHUNK);
            if (tid == 64 && pollIn)
                asm volatile("global_load_dword %0, %1, off sc0 sc1" : "=v"(afv) : "v"(af));
            if (tid == 65 && pollBp)
                asm volatile("global_load_dword %0, %1, off sc0 sc1" : "=v"(bpv) : "v"(consA));
            LGKM0(); SBAR();

            // ---------- 8 inner steps, one barrier each ----------
            for (int s = 0; s < CHUNK; ++s) {
                const int p = s & 1;
                const unsigned short* bsrc = &img[p][hl][8 * g];
                f4 accA = (f4)0.f, accD = (f4)0.f;
                #pragma unroll
                for (int half = 0; half < 2; ++half) {
                    short8 bf[4];
                    #pragma unroll
                    for (int q = 0; q < 4; ++q)
                        bf[q] = *(const short8*)(bsrc + 32 * (4 * half + q));
                    #pragma unroll
                    for (int q = 0; q < 4; ++q) {
                        accA = __builtin_amdgcn_mfma_f32_16x16x32_bf16(waH[4 * half + q], bf[q], accA, 0, 0, 0);
                        accD = __builtin_amdgcn_mfma_f32_16x16x32_bf16(waL[4 * half + q], bf[q], accD, 0, 0, 0);
                    }
                }
                f4 dtot = accA + accD;
                f4 dsum;
                #pragma unroll
                for (int jj = 0; jj < 4; ++jj) dsum[jj] = dpp_ror8_add(dtot[jj], dtot[jj]);
                // all-lane tail (cols redundant); writes spread over cols
                f4 a4 = *(const f4*)&apL[s][m0];
                f4 h4;
                #pragma unroll
                for (int jj = 0; jj < 4; ++jj) h4[jj] = tanh_fast(dsum[jj] + a4[jj]);
                u16x4 hh, ll;
                #pragma unroll
                for (int jj = 0; jj < 4; ++jj) {
                    unsigned short x_ = bf_hi(h4[jj]);
                    hh[jj] = x_;
                    ll[jj] = bf_hi(h4[jj] - bf2f(x_));
                }
                if (col == 0)      *(u16x4*)&img[p ^ 1][0][m0] = hh;
                else if (col == 1) *(u16x4*)&img[p ^ 1][1][m0] = ll;
                else if (col == 2) {
                    if (l < NLAY - 1)
                        st_coh_f4(Hout + (size_t)((k & 7) * CHUNK + s) * HID + m0, h4);
                    else if (k == NCHUNK - 1 && s == CHUNK - 1)
                        st_coh_f4(hfin + m0, h4);
                }
                if (s == 1) {
                    if (tid == 64 && pollIn) { WAIT_PIN(afv); pf_lds[0] = (afv >= (unsigned)(k + 2)); }
                    if (tid == 65 && pollBp) { WAIT_PIN(bpv); pf_lds[1] = (bpv >= (unsigned)(k - 6)); }
                }
                if (s == 2) {
                    havePF = false;
                    if (k + 1 < NCHUNK) {
                        const bool b1 = l0 || (pf_lds[0] != 0);
                        if (b1) {
                            havePF = true;
                            if (l0) {
                                apn0 = Psrc[(size_t)(CHUNK * (k + 1) + sA) * HID + m2];
                                apn1 = Psrc[(size_t)(CHUNK * (k + 1) + sA + 4) * HID + m2];
                            } else {
                                apn0 = ld_coh_b32(apbuf + (size_t)(((k + 1) & 7) * CHUNK + sA) * HID + m2);
                                apn1 = ld_coh_b32(apbuf + (size_t)(((k + 1) & 7) * CHUNK + sA + 4) * HID + m2);
                            }
                        }
                    }
                }
                LGKM0(); SBAR();
            }
            // ---------- drain + publish ----------
            VMW0(); SBAR();
            if (tid == 0) st_coh_u32(myHfl, (unsigned)(k + 1));
        }
    } else {
        // ===================== A role (l = 1..15): 8 timesteps per MFMA batch ==
        const float*    Hin    = Hring + ((size_t)(c * NLAY + (l - 1)) * QS) * HID;
        const unsigned* inflag = Hflag + c * NLAY + (l - 1);
        float*          Aout   = Apart + ((size_t)(c * NLAY + l) * QS) * HID;
        unsigned*       myAfl  = Aflag + c * NLAY + l;
        const unsigned* consB  = Hflag + c * NLAY + l;

        float hn0 = 0.f, hn1 = 0.f;
        bool havePF = false;

        for (int k = 0; k < NCHUNK; ++k) {
            // ---------- chunk top ----------
            int pf2ok = 1;
            if (k >= CHUNK) pf2ok = pf_lds[1];
            const bool needbar = !havePF || !pf2ok;
            if (needbar) {
                if (tid == 0) {
                    if (!havePF) spin_ge(inflag, (unsigned)(k + 1), &dead);
                    if (!pf2ok)  spin_ge(consB, (unsigned)(k - 7), &dead);
                }
                SBAR();
            }
            float h0, h1;
            if (havePF) {
                VMW0();
                h0 = hn0; h1 = hn1;
            } else {
                h0 = ld_coh_b32(Hin + (size_t)((k & 7) * CHUNK + sA) * HID + m2);
                h1 = ld_coh_b32(Hin + (size_t)((k & 7) * CHUNK + sA + 4) * HID + m2);
                VMW0();
            }
            {
                unsigned short x0 = bf_hi(h0), x1 = bf_hi(h1);
                stgH[sA][m2] = x0;     stgL[sA][m2] = bf_hi(h0 - bf2f(x0));
                stgH[sA + 4][m2] = x1; stgL[sA + 4][m2] = bf_hi(h1 - bf2f(x1));
            }
            unsigned inv = 0u, bpv = 0u;
            const bool pollIn = (k + 1 < NCHUNK);
            const bool pollBp = (k + 1 >= CHUNK) && (k + 1 < NCHUNK);
            if (tid == 64 && pollIn)
                asm volatile("global_load_dword %0, %1, off sc0 sc1" : "=v"(inv) : "v"(inflag));
            if (tid == 65 && pollBp)
                asm volatile("global_load_dword %0, %1, off sc0 sc1" : "=v"(bpv) : "v"(consB));
            LGKM0(); SBAR();

            // ---------- one MFMA batch covers all 8 timesteps ----------
            {
                const int ts = col & 7;   // timestep this column serves
                const unsigned short* bsrc = (lane & 8) ? &stgL[ts][8 * g] : &stgH[ts][8 * g];
                f4 accA = (f4)0.f, accD = (f4)0.f;
                #pragma unroll
                for (int half = 0; half < 2; ++half) {
                    short8 bf[4];
                    #pragma unroll
                    for (int q = 0; q < 4; ++q)
                        bf[q] = *(const short8*)(bsrc + 32 * (4 * half + q));
                    #pragma unroll
                    for (int q = 0; q < 4; ++q) {
                        accA = __builtin_amdgcn_mfma_f32_16x16x32_bf16(waH[4 * half + q], bf[q], accA, 0, 0, 0);
                        accD = __builtin_amdgcn_mfma_f32_16x16x32_bf16(waL[4 * half + q], bf[q], accD, 0, 0, 0);
                    }
                }
                f4 dtot = accA + accD;
                f4 dsum;
                #pragma unroll
                for (int jj = 0; jj < 4; ++jj) dsum[jj] = dpp_ror8_add(dtot[jj], dtot[jj]);
                if (!(lane & 8))   // cols 0-7 hold the full 4-term sum for timestep ts
                    st_coh_f4(Aout + (size_t)((k & 7) * CHUNK + ts) * HID + m0, dsum);
            }
            // ---------- polls, drain, publish, prefetch ----------
            if (tid == 64 && pollIn) { WAIT_PIN(inv); pf_lds[0] = (inv >= (unsigned)(k + 2)); }
            if (tid == 65 && pollBp) { WAIT_PIN(bpv); pf_lds[1] = (bpv >= (unsigned)(k - 6)); }
            VMW0(); LGKM0(); SBAR();
            havePF = false;
            if (k + 1 < NCHUNK && pf_lds[0] != 0) {
                havePF = true;
                hn0 = ld_coh_b32(Hin + (size_t)(((k + 1) & 7) * CHUNK + sA) * HID + m2);
                hn1 = ld_coh_b32(Hin + (size_t)(((k + 1) & 7) * CHUNK + sA + 4) * HID + m2);
            }
            if (tid == 0) st_coh_u32(myAfl, (unsigned)(k + 1));
        }
    }
}

// ---------------------------------------------------------------------------
// Kernel 3: out = fc_W @ concat(h0..h3) + fc_b
__global__ __launch_bounds__(1024) void fc_kernel(
    const float* __restrict__ hfinal, const float* __restrict__ fcW,
    const float* __restrict__ fcb, float* __restrict__ out)
{
    __shared__ float red[1024];
    const int tid = threadIdx.x;
    float v  = hfinal[tid];
    float p0 = fcW[tid] * v;
    float p1 = fcW[1024 + tid] * v;

    red[tid] = p0; __syncthreads();
    for (int st = 512; st > 0; st >>= 1) { if (tid < st) red[tid] += red[tid + st]; __syncthreads(); }
    if (tid == 0) out[0] = red[0] + fcb[0];
    __syncthreads();
    red[tid] = p1; __syncthreads();
    for (int st = 512; st > 0; st >>= 1) { if (tid < st) red[tid] += red[tid + st]; __syncthreads(); }
    if (tid == 0) out[1] = red[0] + fcb[1];
}

// ---------------------------------------------------------------------------
extern "C" void kernel_launch(void* const* d_in, const int* in_sizes, int n_in,
                              void* d_out, int out_size, void* d_ws, size_t ws_size,
                              hipStream_t stream)
{
    (void)in_sizes; (void)n_in; (void)out_size; (void)ws_size;
    const float* x        = (const float*)d_in[0];
    const float* lp_Wih0  = (const float*)d_in[1];
    const float* lp_Wih   = (const float*)d_in[2];
    const float* lp_Whh   = (const float*)d_in[3];
    const float* lp_bih   = (const float*)d_in[4];
    const float* lp_bhh   = (const float*)d_in[5];
    const float* lpv_Wih0 = (const float*)d_in[6];
    const float* lpv_Wih  = (const float*)d_in[7];
    const float* lpv_Whh  = (const float*)d_in[8];
    const float* lpv_bih  = (const float*)d_in[9];
    const float* lpv_bhh  = (const float*)d_in[10];
    const float* fcW      = (const float*)d_in[11];
    const float* fcb      = (const float*)d_in[12];

    float* ws      = (float*)d_ws;
    float* Pbuf    = ws + P_OFF;
    float* Hring   = ws + H_OFF;
    float* Apart   = ws + AP_OFF;
    float* hfinal  = ws + HF_OFF;
    unsigned* flags = (unsigned*)(ws + FLAG_OFF_FLOATS);

    hipMemsetAsync(flags, 0, NFLAGS * sizeof(unsigned), stream);

    proj_kernel<<<SEQL / TPB, 1024, 0, stream>>>(x, lp_Wih0, lpv_Wih0, Pbuf);

    rnn_pipe<<<124, 1024, 0, stream>>>(lp_Wih, lp_Whh, lp_bih, lp_bhh,
                                       lpv_Wih, lpv_Whh, lpv_bih, lpv_bhh,
                                       Pbuf, Hring, Apart, hfinal,
                                       flags, flags + 64);

    fc_kernel<<<1, 1024, 0, stream>>>(hfinal, fcW, fcb, (float*)d_out);
}

// Round 19
// 3809.398 us; speedup vs baseline: 1.6944x; 1.6944x over previous
//
#include <hip/hip_runtime.h>
#include <hip/hip_bf16.h>
#include <math.h>

#define SEQL   4096
#define NITEMS 512
#define HID    256
#define NLAY   16
#define QS     64      // ring slots = 8 chunks x 8 steps
#define CHUNK  8
#define NCHUNK (SEQL / CHUNK)
#define TPB    4

typedef float f4 __attribute__((ext_vector_type(4)));

// Workspace layout (float offsets)
#define P_OFF   ((size_t)0)                               // P[4][SEQL][HID]
#define H_OFF   (P_OFF + (size_t)4*SEQL*HID)              // Hring[4][NLAY][QS][HID]
#define AP_OFF  (H_OFF + (size_t)4*NLAY*QS*HID)           // Apart[4][NLAY][QS][HID]
#define HF_OFF  (AP_OFF + (size_t)4*NLAY*QS*HID)          // hfinal[4][HID]
#define FLAG_OFF_FLOATS (HF_OFF + (size_t)1024)
#define NFLAGS 256

// ---------------------------------------------------------------------------
__device__ __forceinline__ float ld_coh_b32(const float* p) {
    float r;
    asm volatile("global_load_dword %0, %1, off sc0 sc1" : "=v"(r) : "v"(p));
    return r;
}
__device__ __forceinline__ void st_coh_b32(float* p, float v) {
    asm volatile("global_store_dword %0, %1, off sc0 sc1" :: "v"(p), "v"(v) : "memory");
}
__device__ __forceinline__ void st_coh_u32(unsigned* p, unsigned v) {
    asm volatile("global_store_dword %0, %1, off sc0 sc1" :: "v"(p), "v"(v) : "memory");
}
__device__ __forceinline__ unsigned uload(const unsigned* p) {
    return __hip_atomic_load(p, __ATOMIC_RELAXED, __HIP_MEMORY_SCOPE_AGENT);
}

#define SBAR()  { __builtin_amdgcn_s_barrier(); __builtin_amdgcn_sched_barrier(0); }
#define LGKM0() { asm volatile("s_waitcnt lgkmcnt(0)" ::: "memory"); __builtin_amdgcn_sched_barrier(0); }
#define VMW0()  { asm volatile("s_waitcnt vmcnt(0)" ::: "memory"); __builtin_amdgcn_sched_barrier(0); }
// Wait own-wave vmem AND pin reg as output so uses can't hoist above (rule 18).
#define WAIT_PIN(reg) { asm volatile("s_waitcnt vmcnt(0)" : "+v"(reg) :: "memory"); \
                        __builtin_amdgcn_sched_barrier(0); }

__device__ __forceinline__ void spin_ge(const unsigned* p, unsigned target, bool* dead) {
    if (*dead) return;
    unsigned it = 0;
    while (uload(p) < target) {
        __builtin_amdgcn_s_sleep(1);
        if (++it > (1u << 20)) { *dead = true; break; }
    }
}

__device__ __forceinline__ float tanh_fast(float x) {
    return 1.f - __fdividef(2.f, __expf(2.f * x) + 1.f);
}

// DPP-FMA: ROW_ROR:i => lane q reads src0 from lane (q-i)&15 (verified R10).
#define FMAC0(ACC, HB, W) \
    asm volatile("v_fmac_f32 %0, %1, %2" : "+v"(ACC) : "v"(HB), "v"(W));
#define FMACR(ACC, HB, W, I) \
    asm volatile("v_fmac_f32_dpp %0, %1, %2 row_ror:" #I " row_mask:0xf bank_mask:0xf" \
                 : "+v"(ACC) : "v"(HB), "v"(W));

#define FMAC_BLOCK(HB, WB) \
    FMAC0(acc0, HB, w[WB+0])      FMACR(acc1, HB, w[WB+1], 1)   \
    FMACR(acc2, HB, w[WB+2], 2)   FMACR(acc3, HB, w[WB+3], 3)   \
    FMACR(acc0, HB, w[WB+4], 4)   FMACR(acc1, HB, w[WB+5], 5)   \
    FMACR(acc2, HB, w[WB+6], 6)   FMACR(acc3, HB, w[WB+7], 7)   \
    FMACR(acc0, HB, w[WB+8], 8)   FMACR(acc1, HB, w[WB+9], 9)   \
    FMACR(acc0, HB, w[WB+10], 10) FMACR(acc1, HB, w[WB+11], 11) \
    FMACR(acc2, HB, w[WB+12], 12) FMACR(acc3, HB, w[WB+13], 13) \
    FMACR(acc2, HB, w[WB+14], 14) FMACR(acc3, HB, w[WB+15], 15)

#define BPERM4(H) \
    { hb0 = __int_as_float(__builtin_amdgcn_ds_bpermute(ab0, __float_as_int(H))); \
      hb1 = __int_as_float(__builtin_amdgcn_ds_bpermute(ab1, __float_as_int(H))); \
      hb2 = __int_as_float(__builtin_amdgcn_ds_bpermute(ab2, __float_as_int(H))); \
      hb3 = __int_as_float(__builtin_amdgcn_ds_bpermute(ab3, __float_as_int(H))); }

// ---------------------------------------------------------------------------
// Kernel 1: input projection P[c][t][j] = sum_k Wih0_c[j,k] * x[t,k,c]
__global__ __launch_bounds__(1024) void proj_kernel(
    const float* __restrict__ x, const float* __restrict__ Wlp,
    const float* __restrict__ Wlpv, float* __restrict__ P)
{
    __shared__ float xs[TPB][4][NITEMS];
    const int tid = threadIdx.x;
    const int t0 = blockIdx.x * TPB;

    #pragma unroll
    for (int tt = 0; tt < TPB; ++tt) {
        const float2* src = (const float2*)(x + (size_t)(t0 + tt) * NITEMS * 4);
        float2 v = src[tid];
        int e = 2 * tid;
        xs[tt][e & 3][e >> 2]       = v.x;
        xs[tt][(e + 1) & 3][e >> 2] = v.y;
    }
    __syncthreads();

    const int c = tid >> 8, j = tid & 255;
    const float* W = (c == 1) ? Wlpv : Wlp;
    const float4* row = (const float4*)(W + (size_t)j * NITEMS);
    float acc[TPB] = {0.f, 0.f, 0.f, 0.f};
    #pragma unroll 4
    for (int k4 = 0; k4 < NITEMS / 4; ++k4) {
        float4 w = row[k4];
        #pragma unroll
        for (int tt = 0; tt < TPB; ++tt) {
            float4 xv = *(const float4*)(&xs[tt][c][k4 * 4]);
            acc[tt] = fmaf(w.x, xv.x, fmaf(w.y, xv.y, fmaf(w.z, xv.z, fmaf(w.w, xv.w, acc[tt]))));
        }
    }
    #pragma unroll
    for (int tt = 0; tt < TPB; ++tt)
        P[((size_t)c * SEQL + (t0 + tt)) * HID + j] = acc[tt];
}

// ---------------------------------------------------------------------------
// Kernel 2: layer-pipelined RNN. Chunked handshakes with EARLY-POLL + NEXT-CHUNK
// PREFETCH (exploits the ring's producer lead); one barrier per inner step;
// DPP matvec; bpermute broadcast. 124 blocks = 4 chains x (16 B + 15 A).
__global__ __launch_bounds__(1024) void rnn_pipe(
    const float* __restrict__ lp_Wih,  const float* __restrict__ lp_Whh,
    const float* __restrict__ lp_bih,  const float* __restrict__ lp_bhh,
    const float* __restrict__ lpv_Wih, const float* __restrict__ lpv_Whh,
    const float* __restrict__ lpv_bih, const float* __restrict__ lpv_bhh,
    const float* __restrict__ P, float* __restrict__ Hring,
    float* __restrict__ Apart, float* __restrict__ hfinal,
    unsigned* __restrict__ Hflag, unsigned* __restrict__ Aflag)
{
    __shared__ __align__(16) float part2[2][1024];
    __shared__ int pf_lds[2];   // [0]=next-chunk data ready, [1]=next-chunk bp ok

    const int b = blockIdx.x;
    if (b >= 124) return;
    const int tid = threadIdx.x;

    const int c = b / 31;
    const int r = b % 31;
    const int role = (r < NLAY) ? 0 : 1;
    const int l = (r < NLAY) ? r : (r - NLAY + 1);

    const float* Wih = (c == 1) ? lpv_Wih : lp_Wih;
    const float* Whh = (c == 1) ? lpv_Whh : lp_Whh;
    const float* bih = (c == 1) ? lpv_bih : lp_bih;
    const float* bhh = (c == 1) ? lpv_bhh : lp_bhh;

    const int j    = tid & 255;
    const int c4   = tid >> 8;
    const int lane = tid & 63;
    const int q    = lane & 15;
    const int m    = (c4 << 6) | lane;
    const bool first = ((tid & 192) == 0);
    bool dead = false;

    const int ab0 = 4 * (q);
    const int ab1 = 4 * (16 + q);
    const int ab2 = 4 * (32 + q);
    const int ab3 = 4 * (48 + q);

    if (role == 0) {
        // ===================== B role =====================
        const bool l0 = (l == 0);

        float w[64];
        {
            const float* Wrow = Whh + ((size_t)l * HID + j) * HID;
            #pragma unroll
            for (int bb = 0; bb < 4; ++bb)
                #pragma unroll
                for (int i = 0; i < 16; ++i)
                    w[bb * 16 + i] = Wrow[(c4 << 6) + bb * 16 + ((q - i) & 15)];
        }
        #pragma unroll
        for (int i = 0; i < 64; ++i) asm volatile("" : "+v"(w[i]));

        const float bias_m = bih[l * HID + m] + bhh[l * HID + m];

        const float*    Psrc  = P + (size_t)c * SEQL * HID;
        const float*    apbuf = Apart + ((size_t)(c * NLAY + l) * QS) * HID;
        const unsigned* af    = Aflag + c * NLAY + l;
        unsigned*       myHfl = Hflag + c * NLAY + l;
        const unsigned* consA = Aflag + c * NLAY + l + 1;   // valid when l<15
        float*          Hout  = Hring + ((size_t)(c * NLAY + l) * QS) * HID;
        float*          hfin  = hfinal + (size_t)c * HID;

        float h = 0.f;
        float hb0, hb1, hb2, hb3;
        float ap8[CHUNK], apn[CHUNK];
        bool havePF = false;

        for (int k = 0; k < NCHUNK; ++k) {
            // ---------- chunk top ----------
            int pf2ok = 1;
            if (k >= CHUNK && l < NLAY - 1) pf2ok = pf_lds[1];
            const bool needbar = (!havePF && !l0) || !pf2ok;
            if (needbar) {
                if (tid == 0) {
                    if (!havePF && !l0) spin_ge(af, (unsigned)(k + 1), &dead);
                    if (!pf2ok) spin_ge(consA, (unsigned)(k - 7), &dead);
                }
                SBAR();
            }
            if (havePF) {
                VMW0();
                #pragma unroll
                for (int s = 0; s < CHUNK; ++s) ap8[s] = apn[s];
            } else {
                if (l0) {
                    #pragma unroll
                    for (int s = 0; s < CHUNK; ++s)
                        ap8[s] = Psrc[(size_t)(CHUNK * k + s) * HID + m];
                } else {
                    const int sbase = (k & 7) * CHUNK;
                    #pragma unroll
                    for (int s = 0; s < CHUNK; ++s)
                        ap8[s] = ld_coh_b32(apbuf + (size_t)(sbase + s) * HID + m);
                    VMW0();
                }
            }
            // issue next-chunk polls (non-blocking; checked at s==1)
            unsigned afv = 0u, bpv = 0u;
            const bool pollIn = (!l0) && (k + 1 < NCHUNK);
            const bool pollBp = (l < NLAY - 1) && (k + 1 >= CHUNK) && (k + 1 < NCHUNK);
            if (tid == 64 && pollIn)
                asm volatile("global_load_dword %0, %1, off sc0 sc1" : "=v"(afv) : "v"(af));
            if (tid == 65 && pollBp)
                asm volatile("global_load_dword %0, %1, off sc0 sc1" : "=v"(bpv) : "v"(consA));

            // ---------- 8 inner steps ----------
            #pragma unroll
            for (int s = 0; s < CHUNK; ++s) {
                BPERM4(h);
                float acc0 = 0.f, acc1 = 0.f, acc2 = 0.f, acc3 = 0.f;
                FMAC_BLOCK(hb0, 0)
                FMAC_BLOCK(hb1, 16)
                FMAC_BLOCK(hb2, 32)
                FMAC_BLOCK(hb3, 48)
                part2[s & 1][tid] = (acc0 + acc1) + (acc2 + acc3);
                LGKM0(); SBAR();
                const float* pb = &part2[s & 1][0];
                float p = pb[m] + pb[m + 256] + pb[m + 512] + pb[m + 768];
                h = tanh_fast(p + ap8[s] + bias_m);
                if (first) {
                    if (l < NLAY - 1)
                        st_coh_b32(Hout + (size_t)((k & 7) * CHUNK + s) * HID + m, h);
                    else if (k == NCHUNK - 1 && s == CHUNK - 1)
                        st_coh_b32(hfin + m, h);
                }
                if (s == 1) {
                    if (tid == 64 && pollIn) { WAIT_PIN(afv); pf_lds[0] = (afv >= (unsigned)(k + 2)); }
                    if (tid == 65 && pollBp) { WAIT_PIN(bpv); pf_lds[1] = (bpv >= (unsigned)(k - 6)); }
                }
                if (s == 2) {
                    havePF = false;
                    if (k + 1 < NCHUNK) {
                        const bool b1 = l0 || (pf_lds[0] != 0);
                        if (b1) {
                            havePF = true;
                            if (l0) {
                                #pragma unroll
                                for (int s2 = 0; s2 < CHUNK; ++s2)
                                    apn[s2] = Psrc[(size_t)(CHUNK * (k + 1) + s2) * HID + m];
                            } else {
                                const int nb = ((k + 1) & 7) * CHUNK;
                                #pragma unroll
                                for (int s2 = 0; s2 < CHUNK; ++s2)
                                    apn[s2] = ld_coh_b32(apbuf + (size_t)(nb + s2) * HID + m);
                            }
                        }
                    }
                }
            }
            // ---------- drain + publish ----------
            if (first) VMW0();
            SBAR();
            if (tid == 0) st_coh_u32(myHfl, (unsigned)(k + 1));
        }
    } else {
        // ===================== A role (l = 1..15) =====================
        float w[64];
        {
            const float* Wrow = Wih + ((size_t)(l - 1) * HID + j) * HID;
            #pragma unroll
            for (int bb = 0; bb < 4; ++bb)
                #pragma unroll
                for (int i = 0; i < 16; ++i)
                    w[bb * 16 + i] = Wrow[(c4 << 6) + bb * 16 + ((q - i) & 15)];
        }
        #pragma unroll
        for (int i = 0; i < 64; ++i) asm volatile("" : "+v"(w[i]));

        const float*    Hin    = Hring + ((size_t)(c * NLAY + (l - 1)) * QS) * HID;
        const unsigned* inflag = Hflag + c * NLAY + (l - 1);
        float*          Aout   = Apart + ((size_t)(c * NLAY + l) * QS) * HID;
        unsigned*       myAfl  = Aflag + c * NLAY + l;
        const unsigned* consB  = Hflag + c * NLAY + l;

        float hb0, hb1, hb2, hb3;
        float h8[CHUNK], h8n[CHUNK];
        bool havePF = false;

        for (int k = 0; k < NCHUNK; ++k) {
            // ---------- chunk top ----------
            int pf2ok = 1;
            if (k >= CHUNK) pf2ok = pf_lds[1];
            const bool needbar = !havePF || !pf2ok;
            if (needbar) {
                if (tid == 0) {
                    if (!havePF) spin_ge(inflag, (unsigned)(k + 1), &dead);
                    if (!pf2ok)  spin_ge(consB, (unsigned)(k - 7), &dead);
                }
                SBAR();
            }
            if (havePF) {
                VMW0();
                #pragma unroll
                for (int s = 0; s < CHUNK; ++s) h8[s] = h8n[s];
            } else {
                const float* hbase = Hin + (size_t)(k & 7) * CHUNK * HID + m;
                #pragma unroll
                for (int s = 0; s < CHUNK; ++s)
                    h8[s] = ld_coh_b32(hbase + (size_t)s * HID);
                VMW0();
            }
            unsigned inv = 0u, bpv = 0u;
            const bool pollIn = (k + 1 < NCHUNK);
            const bool pollBp = (k + 1 >= CHUNK) && (k + 1 < NCHUNK);
            if (tid == 64 && pollIn)
                asm volatile("global_load_dword %0, %1, off sc0 sc1" : "=v"(inv) : "v"(inflag));
            if (tid == 65 && pollBp)
                asm volatile("global_load_dword %0, %1, off sc0 sc1" : "=v"(bpv) : "v"(consB));

            // ---------- 8 inner steps ----------
            #pragma unroll
            for (int s = 0; s < CHUNK; ++s) {
                BPERM4(h8[s]);
                float acc0 = 0.f, acc1 = 0.f, acc2 = 0.f, acc3 = 0.f;
                FMAC_BLOCK(hb0, 0)
                FMAC_BLOCK(hb1, 16)
                FMAC_BLOCK(hb2, 32)
                FMAC_BLOCK(hb3, 48)
                part2[s & 1][tid] = (acc0 + acc1) + (acc2 + acc3);
                LGKM0(); SBAR();
                if (first) {
                    const float* pb = &part2[s & 1][0];
                    float p = pb[m] + pb[m + 256] + pb[m + 512] + pb[m + 768];
                    st_coh_b32(Aout + (size_t)((k & 7) * CHUNK + s) * HID + m, p);
                }
                if (s == 1) {
                    if (tid == 64 && pollIn) { WAIT_PIN(inv); pf_lds[0] = (inv >= (unsigned)(k + 2)); }
                    if (tid == 65 && pollBp) { WAIT_PIN(bpv); pf_lds[1] = (bpv >= (unsigned)(k - 6)); }
                }
                if (s == 2) {
                    havePF = false;
                    if (k + 1 < NCHUNK && pf_lds[0] != 0) {
                        havePF = true;
                        const float* nb = Hin + (size_t)((k + 1) & 7) * CHUNK * HID + m;
                        #pragma unroll
                        for (int s2 = 0; s2 < CHUNK; ++s2)
                            h8n[s2] = ld_coh_b32(nb + (size_t)s2 * HID);
                    }
                }
            }
            // ---------- drain + publish ----------
            if (first) VMW0();
            SBAR();
            if (tid == 0) st_coh_u32(myAfl, (unsigned)(k + 1));
        }
    }
}

// ---------------------------------------------------------------------------
// Kernel 3: out = fc_W @ concat(h0..h3) + fc_b
__global__ __launch_bounds__(1024) void fc_kernel(
    const float* __restrict__ hfinal, const float* __restrict__ fcW,
    const float* __restrict__ fcb, float* __restrict__ out)
{
    __shared__ float red[1024];
    const int tid = threadIdx.x;
    float v  = hfinal[tid];
    float p0 = fcW[tid] * v;
    float p1 = fcW[1024 + tid] * v;

    red[tid] = p0; __syncthreads();
    for (int st = 512; st > 0; st >>= 1) { if (tid < st) red[tid] += red[tid + st]; __syncthreads(); }
    if (tid == 0) out[0] = red[0] + fcb[0];
    __syncthreads();
    red[tid] = p1; __syncthreads();
    for (int st = 512; st > 0; st >>= 1) { if (tid < st) red[tid] += red[tid + st]; __syncthreads(); }
    if (tid == 0) out[1] = red[0] + fcb[1];
}

// ---------------------------------------------------------------------------
extern "C" void kernel_launch(void* const* d_in, const int* in_sizes, int n_in,
                              void* d_out, int out_size, void* d_ws, size_t ws_size,
                              hipStream_t stream)
{
    (void)in_sizes; (void)n_in; (void)out_size; (void)ws_size;
    const float* x        = (const float*)d_in[0];
    const float* lp_Wih0  = (const float*)d_in[1];
    const float* lp_Wih   = (const float*)d_in[2];
    const float* lp_Whh   = (const float*)d_in[3];
    const float* lp_bih   = (const float*)d_in[4];
    const float* lp_bhh   = (const float*)d_in[5];
    const float* lpv_Wih0 = (const float*)d_in[6];
    const float* lpv_Wih  = (const float*)d_in[7];
    const float* lpv_Whh  = (const float*)d_in[8];
    const float* lpv_bih  = (const float*)d_in[9];
    const float* lpv_bhh  = (const float*)d_in[10];
    const float* fcW      = (const float*)d_in[11];
    const float* fcb      = (const float*)d_in[12];

    float* ws      = (float*)d_ws;
    float* Pbuf    = ws + P_OFF;
    float* Hring   = ws + H_OFF;
    float* Apart   = ws + AP_OFF;
    float* hfinal  = ws + HF_OFF;
    unsigned* flags = (unsigned*)(ws + FLAG_OFF_FLOATS);

    hipMemsetAsync(flags, 0, NFLAGS * sizeof(unsigned), stream);

    proj_kernel<<<SEQL / TPB, 1024, 0, stream>>>(x, lp_Wih0, lpv_Wih0, Pbuf);

    rnn_pipe<<<124, 1024, 0, stream>>>(lp_Wih, lp_Whh, lp_bih, lp_bhh,
                                       lpv_Wih, lpv_Whh, lpv_bih, lpv_bhh,
                                       Pbuf, Hring, Apart, hfinal,
                                       flags, flags + 64);

    fc_kernel<<<1, 1024, 0, stream>>>(hfinal, fcW, fcb, (float*)d_out);
}